// Round 1
// baseline (703.659 us; speedup 1.0000x reference)
//
#include <hip/hip_runtime.h>
#include <math.h>

#define BN 8192
#define DD 4096
#define RK 16
#define HIDN 24
#define NCHUNK 32

// ws layout (float offsets)
#define OFF_T0   0
#define OFF_T1   (OFF_T0 + BN*RK)            // 131072
#define OFF_H    (OFF_T1 + BN*RK)            // 262144
#define OFF_XN2  (OFF_H  + BN*HIDN)          // 458752
#define OFF_X0N2 (OFF_XN2 + BN)              // 466944
#define ZCOUNT   (OFF_X0N2 + BN)             // 475136  (zeroed region)
#define OFF_MEAN (ZCOUNT)
#define OFF_INV  (OFF_MEAN + DD)
#define OFF_COEF (OFF_INV + DD)
#define OFF_PS   (OFF_COEF + BN)
#define OFF_PQ   (OFF_PS + NCHUNK*DD)

// ---------------- K1a: per-column partial sums over 256-row chunks ----------
__global__ __launch_bounds__(256) void k1a(const float* __restrict__ g,
                                           float* __restrict__ ps,
                                           float* __restrict__ pq) {
    int ct = blockIdx.x & 15, rc = blockIdx.x >> 4;
    int col = ct * 256 + threadIdx.x;
    size_t base = (size_t)rc * 256 * DD + col;
    float s1 = 0.f, s2 = 0.f;
#pragma unroll 4
    for (int i = 0; i < 256; ++i) {
        float v = g[base + (size_t)i * DD];
        s1 += v;
        s2 = fmaf(v, v, s2);
    }
    ps[rc * DD + col] = s1;
    pq[rc * DD + col] = s2;
}

// ---------------- K1b: finalize mean / inv-std ------------------------------
__global__ __launch_bounds__(256) void k1b(const float* __restrict__ ps,
                                           const float* __restrict__ pq,
                                           float* __restrict__ meanw,
                                           float* __restrict__ invw) {
    int d = blockIdx.x * 256 + threadIdx.x;
    float s1 = 0.f, s2 = 0.f;
#pragma unroll
    for (int i = 0; i < NCHUNK; ++i) {
        s1 += ps[i * DD + d];
        s2 += pq[i * DD + d];
    }
    float mean = s1 / (float)BN;
    float var = (s2 - s1 * s1 / (float)BN) / (float)(BN - 1);
    var = fmaxf(var, 0.f);
    meanw[d] = mean;
    invw[d] = 1.f / (sqrtf(var) + 1e-7f);
}

// ---------------- K2: T0 = x0 @ v0^T (partial, atomics), X0N2 ---------------
__global__ __launch_bounds__(256) void k2(const float* __restrict__ grad,
                                          const float* __restrict__ meanw,
                                          const float* __restrict__ invw,
                                          const float* __restrict__ v0,
                                          float* __restrict__ T0,
                                          float* __restrict__ X0N2) {
    __shared__ float xs[16][1024];   // row-rotated by 4*row floats
    int tid = threadIdx.x;
    int rt = blockIdx.x >> 2, ct = blockIdx.x & 3;
    int row0 = rt * 16, col0 = ct * 1024;
    int c = col0 + tid * 4;
    float4 mv = *(const float4*)(meanw + c);
    float4 iv = *(const float4*)(invw + c);

    for (int row = 0; row < 16; ++row) {
        float4 g = *(const float4*)(grad + (size_t)(row0 + row) * DD + c);
        float4 x;
        x.x = (g.x - mv.x) * iv.x;
        x.y = (g.y - mv.y) * iv.y;
        x.z = (g.z - mv.z) * iv.z;
        x.w = (g.w - mv.w) * iv.w;
        int phys = (tid * 4 + row * 4) & 1023;
        *(float4*)&xs[row][phys] = x;
        float s = x.x * x.x + x.y * x.y + x.z * x.z + x.w * x.w;
#pragma unroll
        for (int off = 32; off; off >>= 1) s += __shfl_down(s, off);
        if ((tid & 63) == 0) atomicAdd(&X0N2[row0 + row], s);
    }
    __syncthreads();

    int row = tid & 15, r = tid >> 4;
    int rot = row * 4;
    const float* vr = v0 + (size_t)r * DD + col0;
    float acc = 0.f;
#pragma unroll 8
    for (int k = 0; k < 1024; k += 4) {
        float4 w = *(const float4*)(vr + k);
        int kk = (k + rot) & 1023;
        float4 x = *(const float4*)&xs[row][kk];
        acc = fmaf(w.x, x.x, acc);
        acc = fmaf(w.y, x.y, acc);
        acc = fmaf(w.z, x.z, acc);
        acc = fmaf(w.w, x.w, acc);
    }
    atomicAdd(&T0[(size_t)(row0 + row) * RK + r], acc);
}

__device__ inline float dotu(const float4* ur, const float* t, float b) {
    float a = b;
#pragma unroll
    for (int rr = 0; rr < 4; ++rr) {
        a = fmaf(ur[rr].x, t[4 * rr + 0], a);
        a = fmaf(ur[rr].y, t[4 * rr + 1], a);
        a = fmaf(ur[rr].z, t[4 * rr + 2], a);
        a = fmaf(ur[rr].w, t[4 * rr + 3], a);
    }
    return a;
}

// ---------------- K3: x1 = relu(b0 + u0·t0); T1 += v1·x1 (atomics) ----------
__global__ __launch_bounds__(256) void k3(const float* __restrict__ T0,
                                          const float* __restrict__ u0,
                                          const float* __restrict__ b0,
                                          const float* __restrict__ v1,
                                          float* __restrict__ T1) {
    __shared__ float xs[16][1024];
    int tid = threadIdx.x;
    int rt = blockIdx.x >> 2, ct = blockIdx.x & 3;
    int row0 = rt * 16, col0 = ct * 1024;
    int c = col0 + tid * 4;
    float4 u[4][4];
#pragma unroll
    for (int cc = 0; cc < 4; ++cc)
#pragma unroll
        for (int rr = 0; rr < 4; ++rr)
            u[cc][rr] = *(const float4*)(u0 + (size_t)(c + cc) * RK + rr * 4);
    float4 bv = *(const float4*)(b0 + c);

    for (int row = 0; row < 16; ++row) {
        float t[16];
#pragma unroll
        for (int r = 0; r < 16; ++r) t[r] = T0[(size_t)(row0 + row) * RK + r];  // uniform
        float4 x;
        x.x = fmaxf(dotu(u[0], t, bv.x), 0.f);
        x.y = fmaxf(dotu(u[1], t, bv.y), 0.f);
        x.z = fmaxf(dotu(u[2], t, bv.z), 0.f);
        x.w = fmaxf(dotu(u[3], t, bv.w), 0.f);
        int phys = (tid * 4 + row * 4) & 1023;
        *(float4*)&xs[row][phys] = x;
    }
    __syncthreads();

    int row = tid & 15, r = tid >> 4;
    int rot = row * 4;
    const float* vr = v1 + (size_t)r * DD + col0;
    float acc = 0.f;
#pragma unroll 8
    for (int k = 0; k < 1024; k += 4) {
        float4 w = *(const float4*)(vr + k);
        int kk = (k + rot) & 1023;
        float4 x = *(const float4*)&xs[row][kk];
        acc = fmaf(w.x, x.x, acc);
        acc = fmaf(w.y, x.y, acc);
        acc = fmaf(w.z, x.z, acc);
        acc = fmaf(w.w, x.w, acc);
    }
    atomicAdd(&T1[(size_t)(row0 + row) * RK + r], acc);
}

// ---------------- K4: XN2[b] = sum_d relu(b1 + u1·t1)^2 ---------------------
__global__ __launch_bounds__(256) void k4(const float* __restrict__ T1,
                                          const float* __restrict__ u1,
                                          const float* __restrict__ b1,
                                          float* __restrict__ XN2) {
    int tid = threadIdx.x;
    int rt = blockIdx.x >> 2, ct = blockIdx.x & 3;
    int row0 = rt * 16, col0 = ct * 1024;
    int c = col0 + tid * 4;
    float4 u[4][4];
#pragma unroll
    for (int cc = 0; cc < 4; ++cc)
#pragma unroll
        for (int rr = 0; rr < 4; ++rr)
            u[cc][rr] = *(const float4*)(u1 + (size_t)(c + cc) * RK + rr * 4);
    float4 bv = *(const float4*)(b1 + c);

    for (int row = 0; row < 16; ++row) {
        float t[16];
#pragma unroll
        for (int r = 0; r < 16; ++r) t[r] = T1[(size_t)(row0 + row) * RK + r];  // uniform
        float4 x;
        x.x = fmaxf(dotu(u[0], t, bv.x), 0.f);
        x.y = fmaxf(dotu(u[1], t, bv.y), 0.f);
        x.z = fmaxf(dotu(u[2], t, bv.z), 0.f);
        x.w = fmaxf(dotu(u[3], t, bv.w), 0.f);
        float s = x.x * x.x + x.y * x.y + x.z * x.z + x.w * x.w;
#pragma unroll
        for (int off = 32; off; off >>= 1) s += __shfl_down(s, off);
        if ((tid & 63) == 0) atomicAdd(&XN2[row0 + row], s);
    }
}

// ---------------- K5a: H += w1 · embed_tile (atomics) -----------------------
__global__ __launch_bounds__(512) void k5a(const float* __restrict__ embed,
                                           const float* __restrict__ w1,
                                           float* __restrict__ H) {
    __shared__ float es[16][1024];
    int tid = threadIdx.x;
    int rt = blockIdx.x >> 2, ct = blockIdx.x & 3;
    int row0 = rt * 16, col0 = ct * 1024;
    int c2 = col0 + tid * 2;
    for (int row = 0; row < 16; ++row) {
        float2 e = *(const float2*)(embed + (size_t)(row0 + row) * DD + c2);
        int phys = (tid * 2 + row * 4) & 1023;
        *(float2*)&es[row][phys] = e;
    }
    __syncthreads();
    if (tid < 384) {
        int row = tid & 15, j = tid >> 4;
        int rot = row * 4;
        const float* wr = w1 + (size_t)j * DD + col0;
        float acc = 0.f;
#pragma unroll 8
        for (int k = 0; k < 1024; k += 4) {
            float4 w = *(const float4*)(wr + k);
            int kk = (k + rot) & 1023;
            float4 x = *(const float4*)&es[row][kk];
            acc = fmaf(w.x, x.x, acc);
            acc = fmaf(w.y, x.y, acc);
            acc = fmaf(w.z, x.z, acc);
            acc = fmaf(w.w, x.w, acc);
        }
        atomicAdd(&H[(size_t)(row0 + row) * HIDN + j], acc);
    }
}

// ---------------- K5b: coeff = sigmoid(w2·relu(H+bw1)+bw2) ------------------
__global__ __launch_bounds__(256) void k5b(const float* __restrict__ H,
                                           const float* __restrict__ bw1,
                                           const float* __restrict__ w2,
                                           const float* __restrict__ bw2,
                                           float* __restrict__ COEF,
                                           float* __restrict__ out) {
    int b = blockIdx.x * 256 + threadIdx.x;
    float z = bw2[0];
#pragma unroll
    for (int j = 0; j < HIDN; ++j) {
        float h = fmaxf(H[(size_t)b * HIDN + j] + bw1[j], 0.f);
        z = fmaf(w2[j], h, z);
    }
    float cf = 1.f / (1.f + expf(-z));
    COEF[b] = cf;
    out[(size_t)BN * DD + b] = cf;
}

// ---------------- K6: final blend + store -----------------------------------
__global__ __launch_bounds__(256) void k6(const float* __restrict__ grad,
                                          const float* __restrict__ meanw,
                                          const float* __restrict__ invw,
                                          const float* __restrict__ T1,
                                          const float* __restrict__ u1,
                                          const float* __restrict__ b1,
                                          const float* __restrict__ XN2,
                                          const float* __restrict__ X0N2,
                                          const float* __restrict__ COEF,
                                          float* __restrict__ out) {
    int tid = threadIdx.x;
    int rt = blockIdx.x >> 2, ct = blockIdx.x & 3;
    int row0 = rt * 16, col0 = ct * 1024;
    int c = col0 + tid * 4;
    float4 u[4][4];
#pragma unroll
    for (int cc = 0; cc < 4; ++cc)
#pragma unroll
        for (int rr = 0; rr < 4; ++rr)
            u[cc][rr] = *(const float4*)(u1 + (size_t)(c + cc) * RK + rr * 4);
    float4 bv = *(const float4*)(b1 + c);
    float4 mv = *(const float4*)(meanw + c);
    float4 iv = *(const float4*)(invw + c);

    for (int row = 0; row < 16; ++row) {
        int b = row0 + row;
        float t[16];
#pragma unroll
        for (int r = 0; r < 16; ++r) t[r] = T1[(size_t)b * RK + r];  // uniform
        float4 g = *(const float4*)(grad + (size_t)b * DD + c);
        float4 x0;
        x0.x = (g.x - mv.x) * iv.x;
        x0.y = (g.y - mv.y) * iv.y;
        x0.z = (g.z - mv.z) * iv.z;
        x0.w = (g.w - mv.w) * iv.w;
        float4 x2;
        x2.x = fmaxf(dotu(u[0], t, bv.x), 0.f);
        x2.y = fmaxf(dotu(u[1], t, bv.y), 0.f);
        x2.z = fmaxf(dotu(u[2], t, bv.z), 0.f);
        x2.w = fmaxf(dotu(u[3], t, bv.w), 0.f);
        float cf = COEF[b];                       // uniform
        float x0n = sqrtf(X0N2[b]) + 1e-8f;       // uniform
        float xn = sqrtf(XN2[b]) + 1e-8f;         // uniform
        float s1 = (1.f - cf) * x0n / xn;
        float4 o;
        o.x = fmaf(s1, x2.x, cf * x0.x);
        o.y = fmaf(s1, x2.y, cf * x0.y);
        o.z = fmaf(s1, x2.z, cf * x0.z);
        o.w = fmaf(s1, x2.w, cf * x0.w);
        *(float4*)(out + (size_t)b * DD + c) = o;
    }
}

extern "C" void kernel_launch(void* const* d_in, const int* in_sizes, int n_in,
                              void* d_out, int out_size, void* d_ws, size_t ws_size,
                              hipStream_t stream) {
    const float* grad = (const float*)d_in[0];
    const float* embed = (const float*)d_in[1];
    const float* u0 = (const float*)d_in[2];
    const float* v0 = (const float*)d_in[3];
    const float* b0 = (const float*)d_in[4];
    const float* u1 = (const float*)d_in[5];
    const float* v1 = (const float*)d_in[6];
    const float* b1 = (const float*)d_in[7];
    const float* w1 = (const float*)d_in[8];
    const float* bw1 = (const float*)d_in[9];
    const float* w2 = (const float*)d_in[10];
    const float* bw2 = (const float*)d_in[11];
    float* out = (float*)d_out;
    float* ws = (float*)d_ws;

    hipMemsetAsync(ws, 0, (size_t)ZCOUNT * sizeof(float), stream);

    // embed pass first so grad (read by k1a just before k2) stays L3-resident
    k5a<<<2048, 512, 0, stream>>>(embed, w1, ws + OFF_H);
    k1a<<<512, 256, 0, stream>>>(grad, ws + OFF_PS, ws + OFF_PQ);
    k1b<<<16, 256, 0, stream>>>(ws + OFF_PS, ws + OFF_PQ, ws + OFF_MEAN, ws + OFF_INV);
    k2<<<2048, 256, 0, stream>>>(grad, ws + OFF_MEAN, ws + OFF_INV, v0,
                                 ws + OFF_T0, ws + OFF_X0N2);
    k3<<<2048, 256, 0, stream>>>(ws + OFF_T0, u0, b0, v1, ws + OFF_T1);
    k4<<<2048, 256, 0, stream>>>(ws + OFF_T1, u1, b1, ws + OFF_XN2);
    k5b<<<32, 256, 0, stream>>>(ws + OFF_H, bw1, w2, bw2, ws + OFF_COEF, out);
    k6<<<2048, 256, 0, stream>>>(grad, ws + OFF_MEAN, ws + OFF_INV, ws + OFF_T1,
                                 u1, b1, ws + OFF_XN2, ws + OFF_X0N2,
                                 ws + OFF_COEF, out);
}

// Round 2
// 686.401 us; speedup vs baseline: 1.0251x; 1.0251x over previous
//
#include <hip/hip_runtime.h>
#include <math.h>

#define BN 8192
#define DD 4096
#define RK 16
#define HIDN 24
#define NCHUNK 32

// ws layout (float offsets). ps/pq alias T0T/T1T (re-zeroed after k1b).
#define OFF_T0T  0                           // 16*BN = 131072  (also ps)
#define OFF_T1T  (OFF_T0T + RK*BN)           // 131072          (also pq)
#define OFF_H    (OFF_T1T + RK*BN)           // 262144 (BN*HIDN = 196608)
#define OFF_XN2  (OFF_H  + BN*HIDN)          // 458752
#define OFF_X0N2 (OFF_XN2 + BN)              // 466944
#define ZCOUNT   (OFF_X0N2 + BN)             // 475136  (zeroed region)
#define OFF_V1T  (ZCOUNT)                    // 475136 (DD*RK = 65536)
#define OFF_MEAN (OFF_V1T + DD*RK)           // 540672
#define OFF_INV  (OFF_MEAN + DD)             // 544768
#define OFF_COEF (OFF_INV + DD)              // 548864
// total 557056 floats = 2.23 MB (< prior proven 2.95 MB footprint)

// ---------------- kT: v1 [16][4096] -> v1T [4096][16] -----------------------
__global__ __launch_bounds__(256) void kT(const float* __restrict__ v1,
                                          float* __restrict__ v1T) {
    int d = blockIdx.x * 256 + threadIdx.x;
    float v[16];
#pragma unroll
    for (int s = 0; s < 16; ++s) v[s] = v1[(size_t)s * DD + d];
#pragma unroll
    for (int s = 0; s < 4; ++s)
        *(float4*)(v1T + (size_t)d * 16 + s * 4) =
            make_float4(v[4 * s], v[4 * s + 1], v[4 * s + 2], v[4 * s + 3]);
}

// ---------------- K1a: per-column partial sums over 256-row chunks ----------
__global__ __launch_bounds__(256) void k1a(const float* __restrict__ g,
                                           float* __restrict__ ps,
                                           float* __restrict__ pq) {
    int ct = blockIdx.x & 15, rc = blockIdx.x >> 4;
    int col = ct * 256 + threadIdx.x;
    size_t base = (size_t)rc * 256 * DD + col;
    float s1 = 0.f, s2 = 0.f;
#pragma unroll 4
    for (int i = 0; i < 256; ++i) {
        float v = g[base + (size_t)i * DD];
        s1 += v;
        s2 = fmaf(v, v, s2);
    }
    ps[rc * DD + col] = s1;
    pq[rc * DD + col] = s2;
}

// ---------------- K1b: finalize mean / inv-std ------------------------------
__global__ __launch_bounds__(256) void k1b(const float* __restrict__ ps,
                                           const float* __restrict__ pq,
                                           float* __restrict__ meanw,
                                           float* __restrict__ invw) {
    int d = blockIdx.x * 256 + threadIdx.x;
    float s1 = 0.f, s2 = 0.f;
#pragma unroll
    for (int i = 0; i < NCHUNK; ++i) {
        s1 += ps[i * DD + d];
        s2 += pq[i * DD + d];
    }
    float mean = s1 / (float)BN;
    float var = (s2 - s1 * s1 / (float)BN) / (float)(BN - 1);
    var = fmaxf(var, 0.f);
    meanw[d] = mean;
    invw[d] = 1.f / (sqrtf(var) + 1e-7f);
}

// ---------------- K2: T0T[r][b] += v0·x0 (4 accs/thread), X0N2 --------------
__global__ __launch_bounds__(256) void k2(const float* __restrict__ grad,
                                          const float* __restrict__ meanw,
                                          const float* __restrict__ invw,
                                          const float* __restrict__ v0,
                                          float* __restrict__ T0T,
                                          float* __restrict__ X0N2) {
    __shared__ float xs[16][1024];   // row-rotated by 4*row floats
    int tid = threadIdx.x;
    int rt = blockIdx.x >> 2, ct = blockIdx.x & 3;
    int row0 = rt * 16, col0 = ct * 1024;
    int c = col0 + tid * 4;
    float4 mv = *(const float4*)(meanw + c);
    float4 iv = *(const float4*)(invw + c);

    for (int row = 0; row < 16; ++row) {
        float4 g = *(const float4*)(grad + (size_t)(row0 + row) * DD + c);
        float4 x;
        x.x = (g.x - mv.x) * iv.x;
        x.y = (g.y - mv.y) * iv.y;
        x.z = (g.z - mv.z) * iv.z;
        x.w = (g.w - mv.w) * iv.w;
        int phys = (tid * 4 + row * 4) & 1023;
        *(float4*)&xs[row][phys] = x;
        float s = x.x * x.x + x.y * x.y + x.z * x.z + x.w * x.w;
#pragma unroll
        for (int off = 32; off; off >>= 1) s += __shfl_down(s, off);
        if ((tid & 63) == 0) atomicAdd(&X0N2[row0 + row], s);
    }
    __syncthreads();

    // dot phase: thread = (row, g=r-group of 4, ks=k-quarter)
    int row = tid & 15, q = tid >> 4;
    int g = q & 3, ks = q >> 2;
    int rot = row * 4, kbase = ks * 256;
    const float* vbase = v0 + col0 + kbase;
    float acc[4] = {0.f, 0.f, 0.f, 0.f};
#pragma unroll 4
    for (int k = 0; k < 256; k += 4) {
        int kk = (kbase + k + rot) & 1023;
        float4 x = *(const float4*)&xs[row][kk];
#pragma unroll
        for (int rr = 0; rr < 4; ++rr) {
            float4 w = *(const float4*)(vbase + (size_t)(g * 4 + rr) * DD + k);
            acc[rr] = fmaf(w.x, x.x, fmaf(w.y, x.y,
                      fmaf(w.z, x.z, fmaf(w.w, x.w, acc[rr]))));
        }
    }
#pragma unroll
    for (int rr = 0; rr < 4; ++rr)
        atomicAdd(&T0T[(size_t)(g * 4 + rr) * BN + row0 + row], acc[rr]);
}

// ---------------- K3: T1T[s][b] += v1T·relu(b0+u0·t0)  (no LDS) -------------
// thread = row b; weights are wave-uniform -> scalar loads
__global__ __launch_bounds__(256) void k3(const float* __restrict__ T0T,
                                          const float* __restrict__ u0,
                                          const float* __restrict__ b0,
                                          const float* __restrict__ v1T,
                                          float* __restrict__ T1T) {
    int b = (blockIdx.x >> 5) * 256 + threadIdx.x;
    int d0 = (blockIdx.x & 31) * 128;
    float t0[16];
#pragma unroll
    for (int r = 0; r < 16; ++r) t0[r] = T0T[(size_t)r * BN + b];
    float acc[16];
#pragma unroll
    for (int s = 0; s < 16; ++s) acc[s] = 0.f;
#pragma unroll 2
    for (int d = d0; d < d0 + 128; ++d) {
        const float* ur = u0 + (size_t)d * RK;       // uniform
        float x1 = b0[d];
#pragma unroll
        for (int r = 0; r < 16; ++r) x1 = fmaf(ur[r], t0[r], x1);
        x1 = fmaxf(x1, 0.f);
        const float* vr = v1T + (size_t)d * RK;      // uniform
#pragma unroll
        for (int s = 0; s < 16; ++s) acc[s] = fmaf(vr[s], x1, acc[s]);
    }
#pragma unroll
    for (int s = 0; s < 16; ++s)
        atomicAdd(&T1T[(size_t)s * BN + b], acc[s]);
}

// ---------------- K4: XN2[b] += sum_d relu(b1+u1·t1)^2  (no LDS) ------------
__global__ __launch_bounds__(256) void k4(const float* __restrict__ T1T,
                                          const float* __restrict__ u1,
                                          const float* __restrict__ b1,
                                          float* __restrict__ XN2) {
    int b = (blockIdx.x >> 5) * 256 + threadIdx.x;
    int d0 = (blockIdx.x & 31) * 128;
    float t1[16];
#pragma unroll
    for (int r = 0; r < 16; ++r) t1[r] = T1T[(size_t)r * BN + b];
    float acc = 0.f;
#pragma unroll 2
    for (int d = d0; d < d0 + 128; ++d) {
        const float* ur = u1 + (size_t)d * RK;       // uniform
        float x = b1[d];
#pragma unroll
        for (int r = 0; r < 16; ++r) x = fmaf(ur[r], t1[r], x);
        x = fmaxf(x, 0.f);
        acc = fmaf(x, x, acc);
    }
    atomicAdd(&XN2[b], acc);
}

// ---------------- K5a: H += w1·embed_tile (6 accs/thread) -------------------
__global__ __launch_bounds__(256) void k5a(const float* __restrict__ embed,
                                           const float* __restrict__ w1,
                                           float* __restrict__ H) {
    __shared__ float es[16][1024];
    int tid = threadIdx.x;
    int rt = blockIdx.x >> 2, ct = blockIdx.x & 3;
    int row0 = rt * 16, col0 = ct * 1024;
    int c = col0 + tid * 4;
    for (int row = 0; row < 16; ++row) {
        float4 e = *(const float4*)(embed + (size_t)(row0 + row) * DD + c);
        int phys = (tid * 4 + row * 4) & 1023;
        *(float4*)&es[row][phys] = e;
    }
    __syncthreads();

    int row = tid & 15, q = tid >> 4;
    int g = q & 3, ks = q >> 2;           // j = g*6+jj, k-quarter ks
    int rot = row * 4, kbase = ks * 256;
    const float* wbase = w1 + col0 + kbase;
    float acc[6] = {0.f, 0.f, 0.f, 0.f, 0.f, 0.f};
#pragma unroll 4
    for (int k = 0; k < 256; k += 4) {
        int kk = (kbase + k + rot) & 1023;
        float4 x = *(const float4*)&es[row][kk];
#pragma unroll
        for (int jj = 0; jj < 6; ++jj) {
            float4 w = *(const float4*)(wbase + (size_t)(g * 6 + jj) * DD + k);
            acc[jj] = fmaf(w.x, x.x, fmaf(w.y, x.y,
                      fmaf(w.z, x.z, fmaf(w.w, x.w, acc[jj]))));
        }
    }
#pragma unroll
    for (int jj = 0; jj < 6; ++jj)
        atomicAdd(&H[(size_t)(row0 + row) * HIDN + g * 6 + jj], acc[jj]);
}

// ---------------- K5b: coeff = sigmoid(w2·relu(H+bw1)+bw2) ------------------
__global__ __launch_bounds__(256) void k5b(const float* __restrict__ H,
                                           const float* __restrict__ bw1,
                                           const float* __restrict__ w2,
                                           const float* __restrict__ bw2,
                                           float* __restrict__ COEF,
                                           float* __restrict__ out) {
    int b = blockIdx.x * 256 + threadIdx.x;
    float z = bw2[0];
#pragma unroll
    for (int j = 0; j < HIDN; ++j) {
        float h = fmaxf(H[(size_t)b * HIDN + j] + bw1[j], 0.f);
        z = fmaf(w2[j], h, z);
    }
    float cf = 1.f / (1.f + expf(-z));
    COEF[b] = cf;
    out[(size_t)BN * DD + b] = cf;
}

__device__ inline float dotu(const float4* ur, const float* t, float b) {
    float a = b;
#pragma unroll
    for (int rr = 0; rr < 4; ++rr) {
        a = fmaf(ur[rr].x, t[4 * rr + 0], a);
        a = fmaf(ur[rr].y, t[4 * rr + 1], a);
        a = fmaf(ur[rr].z, t[4 * rr + 2], a);
        a = fmaf(ur[rr].w, t[4 * rr + 3], a);
    }
    return a;
}

// ---------------- K6: final blend + store -----------------------------------
__global__ __launch_bounds__(256) void k6(const float* __restrict__ grad,
                                          const float* __restrict__ meanw,
                                          const float* __restrict__ invw,
                                          const float* __restrict__ T1T,
                                          const float* __restrict__ u1,
                                          const float* __restrict__ b1,
                                          const float* __restrict__ XN2,
                                          const float* __restrict__ X0N2,
                                          const float* __restrict__ COEF,
                                          float* __restrict__ out) {
    int tid = threadIdx.x;
    int rt = blockIdx.x >> 2, ct = blockIdx.x & 3;
    int row0 = rt * 16, col0 = ct * 1024;
    int c = col0 + tid * 4;
    float4 u[4][4];
#pragma unroll
    for (int cc = 0; cc < 4; ++cc)
#pragma unroll
        for (int rr = 0; rr < 4; ++rr)
            u[cc][rr] = *(const float4*)(u1 + (size_t)(c + cc) * RK + rr * 4);
    float4 bv = *(const float4*)(b1 + c);
    float4 mv = *(const float4*)(meanw + c);
    float4 iv = *(const float4*)(invw + c);

    for (int row = 0; row < 16; ++row) {
        int b = row0 + row;
        float t[16];
#pragma unroll
        for (int r = 0; r < 16; ++r) t[r] = T1T[(size_t)r * BN + b];  // uniform
        float4 g = *(const float4*)(grad + (size_t)b * DD + c);
        float4 x0;
        x0.x = (g.x - mv.x) * iv.x;
        x0.y = (g.y - mv.y) * iv.y;
        x0.z = (g.z - mv.z) * iv.z;
        x0.w = (g.w - mv.w) * iv.w;
        float4 x2;
        x2.x = fmaxf(dotu(u[0], t, bv.x), 0.f);
        x2.y = fmaxf(dotu(u[1], t, bv.y), 0.f);
        x2.z = fmaxf(dotu(u[2], t, bv.z), 0.f);
        x2.w = fmaxf(dotu(u[3], t, bv.w), 0.f);
        float cf = COEF[b];                       // uniform
        float x0n = sqrtf(X0N2[b]) + 1e-8f;       // uniform
        float xn = sqrtf(XN2[b]) + 1e-8f;         // uniform
        float s1 = (1.f - cf) * x0n / xn;
        float4 o;
        o.x = fmaf(s1, x2.x, cf * x0.x);
        o.y = fmaf(s1, x2.y, cf * x0.y);
        o.z = fmaf(s1, x2.z, cf * x0.z);
        o.w = fmaf(s1, x2.w, cf * x0.w);
        *(float4*)(out + (size_t)b * DD + c) = o;
    }
}

extern "C" void kernel_launch(void* const* d_in, const int* in_sizes, int n_in,
                              void* d_out, int out_size, void* d_ws, size_t ws_size,
                              hipStream_t stream) {
    const float* grad = (const float*)d_in[0];
    const float* embed = (const float*)d_in[1];
    const float* u0 = (const float*)d_in[2];
    const float* v0 = (const float*)d_in[3];
    const float* b0 = (const float*)d_in[4];
    const float* u1 = (const float*)d_in[5];
    const float* v1 = (const float*)d_in[6];
    const float* b1 = (const float*)d_in[7];
    const float* w1 = (const float*)d_in[8];
    const float* bw1 = (const float*)d_in[9];
    const float* w2 = (const float*)d_in[10];
    const float* bw2 = (const float*)d_in[11];
    float* out = (float*)d_out;
    float* ws = (float*)d_ws;

    hipMemsetAsync(ws, 0, (size_t)ZCOUNT * sizeof(float), stream);

    kT<<<16, 256, 0, stream>>>(v1, ws + OFF_V1T);
    // embed pass first so grad (read by k1a just before k2) stays L3-resident
    k5a<<<2048, 256, 0, stream>>>(embed, w1, ws + OFF_H);
    k1a<<<512, 256, 0, stream>>>(grad, ws + OFF_T0T, ws + OFF_T1T);  // ps/pq alias
    k1b<<<16, 256, 0, stream>>>(ws + OFF_T0T, ws + OFF_T1T, ws + OFF_MEAN, ws + OFF_INV);
    // re-zero T0T/T1T (clobbered by ps/pq) before accumulation
    hipMemsetAsync(ws + OFF_T0T, 0, (size_t)(2 * RK * BN) * sizeof(float), stream);
    k2<<<2048, 256, 0, stream>>>(grad, ws + OFF_MEAN, ws + OFF_INV, v0,
                                 ws + OFF_T0T, ws + OFF_X0N2);
    k3<<<1024, 256, 0, stream>>>(ws + OFF_T0T, u0, b0, ws + OFF_V1T, ws + OFF_T1T);
    k4<<<1024, 256, 0, stream>>>(ws + OFF_T1T, u1, b1, ws + OFF_XN2);
    k5b<<<32, 256, 0, stream>>>(ws + OFF_H, bw1, w2, bw2, ws + OFF_COEF, out);
    k6<<<2048, 256, 0, stream>>>(grad, ws + OFF_MEAN, ws + OFF_INV, ws + OFF_T1T,
                                 u1, b1, ws + OFF_XN2, ws + OFF_X0N2,
                                 ws + OFF_COEF, out);
}